// Round 10
// baseline (253.273 us; speedup 1.0000x reference)
//
#include <hip/hip_runtime.h>
#include <hip/hip_bf16.h>

#define N_Q 256
#define M_S 1024
#define DD 512
#define HH 512

typedef __attribute__((ext_vector_type(8))) short short8;
typedef __attribute__((ext_vector_type(8))) __bf16 bf16x8;
typedef __attribute__((ext_vector_type(16))) float f32x16;
typedef __attribute__((ext_vector_type(2))) __bf16 bf16x2;

union U8 { short8 s; bf16x8 b; };

__device__ __forceinline__ unsigned short f2bf(float f) {
  unsigned int u = __float_as_uint(f);
  u += 0x7FFFu + ((u >> 16) & 1u);
  return (unsigned short)(u >> 16);
}

__device__ __forceinline__ short8 pack8(const float* d) {
#if defined(__has_builtin) && __has_builtin(__builtin_amdgcn_cvt_pk_bf16_f32)
  short8 r;
#pragma unroll
  for (int i = 0; i < 4; ++i) {
    union { bf16x2 v; short s[2]; } u;
    u.v = __builtin_amdgcn_cvt_pk_bf16_f32(d[2 * i], d[2 * i + 1]);
    r[2 * i] = u.s[0];
    r[2 * i + 1] = u.s[1];
  }
  return r;
#else
  short8 r;
#pragma unroll
  for (int i = 0; i < 8; ++i) r[i] = (short)f2bf(d[i]);
  return r;
#endif
}

__device__ __forceinline__ short8 packdiff(float4 e0, float4 e1, float4 s0, float4 s1) {
  float d[8];
  d[0] = fabsf(e0.x - s0.x); d[1] = fabsf(e0.y - s0.y);
  d[2] = fabsf(e0.z - s0.z); d[3] = fabsf(e0.w - s0.w);
  d[4] = fabsf(e1.x - s1.x); d[5] = fabsf(e1.y - s1.y);
  d[6] = fabsf(e1.z - s1.z); d[7] = fabsf(e1.w - s1.w);
  return pack8(d);
}

// W1 [D][H] fp32 -> w1s in MFMA-B-fragment order (verified R3-R8), vectorized.
// Frag f = kc*16 + h32; elem (lane l, j) = W1[kc*16 + (l>>5)*8 + j][h32*32 + (l&31)].
__global__ __launch_bounds__(512) void prep_w1s(const float* __restrict__ W1,
                                                unsigned short* __restrict__ w1s) {
  const int f = blockIdx.x * 8 + (threadIdx.x >> 6);   // 0..511
  const int l = threadIdx.x & 63;
  const int kc = f >> 4, h32 = f & 15;
  const int h = h32 * 32 + (l & 31);
  const int kb = kc * 16 + (l >> 5) * 8;
  short8 v;
#pragma unroll
  for (int j = 0; j < 8; ++j) v[j] = (short)f2bf(W1[(kb + j) * HH + h]);
  *(short8*)(w1s + f * 512 + l * 8) = v;
}

// Block: 512 thr = 8 waves. Tile 128 pairs (8n x 16m) x 256 h (hz split) x
// FULL K=512 (K may NOT be split across blocks: relu is nonlinear).
// A staged in two 64 KB halves (128p x 256k each), [p][c ^ (p&7)] 16B chunks.
// Wave tile 64p x 64h -> acc[2][2] = 64 AGPR; B register-direct from w1s,
// depth-2 rotating on the GLOBAL k-step (prefetch crosses the restage).
// ~120 regs/wave -> 4 waves/SIMD, 2 blocks/CU. 5 barriers/block.
__global__ __launch_bounds__(512, 4) void support_kernel(
    const float* __restrict__ emb, const float* __restrict__ sup,
    const unsigned short* __restrict__ w1s, const float* __restrict__ b1,
    const float* __restrict__ W2, float* __restrict__ out) {
  __shared__ short8 As16[128 * 32];  // [p 0..127][chunk' 0..31], 65536 B

  const int tid = threadIdx.x;
  const int lane = tid & 63;
  const int wid = tid >> 6;          // 0..7
  const int wm = wid & 1;            // pair half (64)
  const int wh = wid >> 1;           // 0..3 : 64-h slice within the 256-h half
  const int l31 = lane & 31;
  const int khalf = lane >> 5;

  const int m0 = blockIdx.x * 16;
  const int n0 = blockIdx.y * 8;
  const int hz = blockIdx.z;         // h half (0..1)

  // ---- B prologue (gks=0,1) issued BEFORE staging ----
  // frag f = gks*16 + hz*8 + wh*2 + tj
  const unsigned short* bb = w1s + (hz * 8 + wh * 2) * 512 + lane * 8;
  U8 b[3][2];
#pragma unroll
  for (int tj = 0; tj < 2; ++tj) {
    b[0][tj].s = *(const short8*)(bb + (0 * 16 + tj) * 512);
    b[1][tj].s = *(const short8*)(bb + (1 * 16 + tj) * 512);
  }

  // staging map: c = 16B k-chunk (0..31), rg = tid>>5 -> 8 rows each
  const int c = tid & 31;
  const int rg = tid >> 5;           // 0..15
  const int nl = rg >> 1;            // 0..7
  const int mq = rg & 1;             // 0..1
  const float* ep_ = emb + (n0 + nl) * DD + c * 8;
  const float* sp_ = sup + (m0 + mq * 8) * DD + c * 8;

  const int ar0 = (wm * 64 + l31) * 32;          // A row base, am=0 (short8 units)
  const int ar1 = (wm * 64 + 32 + l31) * 32;
  const int ax = l31 & 7;

  f32x16 acc[2][2] = {};
  U8 a[2][2];

#pragma unroll
  for (int kh = 0; kh < 2; ++kh) {
    if (kh) __syncthreads();         // prior half's reads complete
    // ---- stage 128p x 256k diffs for this k-half ----
    {
      const float4 e0 = *(const float4*)(ep_ + kh * 256);
      const float4 e1 = *(const float4*)(ep_ + kh * 256 + 4);
#pragma unroll
      for (int j = 0; j < 8; ++j) {
        const float* sp = sp_ + j * DD + kh * 256;
        const float4 s0 = *(const float4*)sp;
        const float4 s1 = *(const float4*)(sp + 4);
        const int p = nl * 16 + mq * 8 + j;      // p&7 == j
        As16[p * 32 + (c ^ j)] = packdiff(e0, e1, s0, s1);
      }
    }
    __syncthreads();                 // tile visible

    a[0][0].s = As16[ar0 + (khalf ^ ax)];
    a[0][1].s = As16[ar1 + (khalf ^ ax)];

#pragma unroll
    for (int ks = 0; ks < 16; ++ks) {
      const int gks = kh * 16 + ks;  // global k-step (B index)
      const int cur = ks & 1;
      if (ks < 15) {                 // A lookahead depth 1 (LDS, this half)
        const int cc = ((ks + 1) * 2 + khalf) ^ ax;
        a[cur ^ 1][0].s = As16[ar0 + cc];
        a[cur ^ 1][1].s = As16[ar1 + cc];
      }
      if (gks + 2 < 32) {            // B lookahead depth 2 (global, crosses halves)
#pragma unroll
        for (int tj = 0; tj < 2; ++tj)
          b[(gks + 2) % 3][tj].s = *(const short8*)(bb + ((gks + 2) * 16 + tj) * 512);
      }
#pragma unroll
      for (int am = 0; am < 2; ++am)
#pragma unroll
        for (int tj = 0; tj < 2; ++tj)
          acc[am][tj] = __builtin_amdgcn_mfma_f32_32x32x16_bf16(
              a[cur][am].b, b[gks % 3][tj].b, acc[am][tj], 0, 0, 0);
    }
  }

  // ---- epilogue: partial over this block's 256 h -> psums -> atomicAdd ----
  float b1v[2], w2v[2];
#pragma unroll
  for (int tj = 0; tj < 2; ++tj) {
    const int h = hz * 256 + (wh * 2 + tj) * 32 + l31;  // C/D: col = lane&31
    b1v[tj] = b1[h];
    w2v[tj] = W2[h];
  }
  __syncthreads();  // all As16 reads done before aliasing
  float* psums = (float*)As16;  // [128 pairs][4 wh]
#pragma unroll
  for (int am = 0; am < 2; ++am) {
#pragma unroll
    for (int r = 0; r < 16; ++r) {
      float s = fmaxf(acc[am][0][r] + b1v[0], 0.f) * w2v[0] +
                fmaxf(acc[am][1][r] + b1v[1], 0.f) * w2v[1];
      s += __shfl_xor(s, 1, 64);
      s += __shfl_xor(s, 2, 64);
      s += __shfl_xor(s, 4, 64);
      s += __shfl_xor(s, 8, 64);
      s += __shfl_xor(s, 16, 64);
      if (l31 == 0) {
        const int row32 = (r & 3) + 8 * (r >> 2) + 4 * khalf;  // C/D row map
        psums[(wm * 64 + am * 32 + row32) * 4 + wh] = s;
      }
    }
  }
  __syncthreads();
  if (tid < 128) {
    const float v = psums[tid * 4] + psums[tid * 4 + 1] +
                    psums[tid * 4 + 2] + psums[tid * 4 + 3];
    atomicAdd(out + (n0 + (tid >> 4)) * M_S + m0 + (tid & 15), v);
  }
}

__global__ __launch_bounds__(256) void logits_finalize(float* __restrict__ out,
                                                       const float* __restrict__ b2) {
  const int i = blockIdx.x * 256 + threadIdx.x;
  const float t = out[i] + b2[0];
  out[i] = 1.f / (1.f + __expf(-t));
}

extern "C" void kernel_launch(void* const* d_in, const int* in_sizes, int n_in,
                              void* d_out, int out_size, void* d_ws, size_t ws_size,
                              hipStream_t stream) {
  const float* emb = (const float*)d_in[0];
  const float* sup = (const float*)d_in[1];
  const float* W1  = (const float*)d_in[2];
  const float* b1  = (const float*)d_in[3];
  const float* W2  = (const float*)d_in[4];
  const float* b2  = (const float*)d_in[5];
  float* out = (float*)d_out;
  unsigned short* w1s = (unsigned short*)d_ws;  // 512 KB fragment-ordered W1

  prep_w1s<<<64, 512, 0, stream>>>(W1, w1s);
  hipMemsetAsync(d_out, 0, (size_t)N_Q * M_S * sizeof(float), stream);
  support_kernel<<<dim3(M_S / 16, N_Q / 8, 2), 512, 0, stream>>>(
      emb, sup, w1s, b1, W2, out);
  logits_finalize<<<(N_Q * M_S) / 256, 256, 0, stream>>>(out, b2);
}

// Round 11
// 236.045 us; speedup vs baseline: 1.0730x; 1.0730x over previous
//
#include <hip/hip_runtime.h>
#include <hip/hip_bf16.h>

#define N_Q 256
#define M_S 1024
#define DD 512
#define HH 512

typedef __attribute__((ext_vector_type(8))) short short8;
typedef __attribute__((ext_vector_type(8))) __bf16 bf16x8;
typedef __attribute__((ext_vector_type(16))) float f32x16;
typedef __attribute__((ext_vector_type(2))) __bf16 bf16x2;

union U8 { short8 s; bf16x8 b; };

__device__ __forceinline__ unsigned short f2bf(float f) {
  unsigned int u = __float_as_uint(f);
  u += 0x7FFFu + ((u >> 16) & 1u);
  return (unsigned short)(u >> 16);
}

__device__ __forceinline__ short8 pack8(const float* d) {
#if defined(__has_builtin) && __has_builtin(__builtin_amdgcn_cvt_pk_bf16_f32)
  short8 r;
#pragma unroll
  for (int i = 0; i < 4; ++i) {
    union { bf16x2 v; short s[2]; } u;
    u.v = __builtin_amdgcn_cvt_pk_bf16_f32(d[2 * i], d[2 * i + 1]);
    r[2 * i] = u.s[0];
    r[2 * i + 1] = u.s[1];
  }
  return r;
#else
  short8 r;
#pragma unroll
  for (int i = 0; i < 8; ++i) r[i] = (short)f2bf(d[i]);
  return r;
#endif
}

__device__ __forceinline__ short8 packdiff(float4 e0, float4 e1, float4 s0, float4 s1) {
  float d[8];
  d[0] = fabsf(e0.x - s0.x); d[1] = fabsf(e0.y - s0.y);
  d[2] = fabsf(e0.z - s0.z); d[3] = fabsf(e0.w - s0.w);
  d[4] = fabsf(e1.x - s1.x); d[5] = fabsf(e1.y - s1.y);
  d[6] = fabsf(e1.z - s1.z); d[7] = fabsf(e1.w - s1.w);
  return pack8(d);
}

// W1 [D][H] fp32 -> w1s in MFMA-B-fragment order (spec verified R3-R8):
// Frag f = kc*16 + h32; elem (lane l, j) = W1[kc*16 + (l>>5)*8 + j][h32*32 + (l&31)].
// v2: LDS-transposed — W1 read flat-coalesced (float4), fragments written as
// coalesced 16B stores. 32 blocks x 512 thr, one 16x512 k-slab per block.
__global__ __launch_bounds__(512) void prep_w1s(const float* __restrict__ W1,
                                                unsigned short* __restrict__ w1s) {
  __shared__ float tile[16 * 516];   // [k 0..15][h 0..511], stride 516 (33 KB)
  const int t = threadIdx.x;
  const int kc = blockIdx.x;         // 0..31
  const float* src = W1 + kc * 16 * HH;   // 16 contiguous rows = 8192 floats
#pragma unroll
  for (int pass = 0; pass < 4; ++pass) {  // flat-coalesced load
    const int fi = pass * 2048 + t * 4;
    const float4 v = *(const float4*)(src + fi);
    *(float4*)&tile[(fi >> 9) * 516 + (fi & 511)] = v;
  }
  __syncthreads();
  const int l = t & 63, h32g = t >> 6;    // h32 group 0..7
  const int l31 = l & 31, kh = l >> 5;
#pragma unroll
  for (int i = 0; i < 2; ++i) {
    const int h32 = i * 8 + h32g;         // 0..15
    short8 v;
#pragma unroll
    for (int j = 0; j < 8; ++j)
      v[j] = (short)f2bf(tile[(kh * 8 + j) * 516 + h32 * 32 + l31]);
    *(short8*)(w1s + (kc * 16 + h32) * 512 + l * 8) = v;  // coalesced 16B
  }
}

// ==== support_kernel: byte-identical to R8 (best: 181.6 us, VGPR 56,
// 4 waves/SIMD, 2 blocks/CU, 3 barriers) ====
// Block: 512 thr = 8 waves. Tile 64 pairs x 512 h x full K=512.
// A (diff) staged ONCE into exactly 64 KB LDS, layout [p][c ^ (p&7)] in 16B
// chunks. Each wave: 64p x 64h -> acc[2][2] = 64 AGPR; B register-direct from
// w1s, depth-2 lookahead.
__global__ __launch_bounds__(512, 4) void support_kernel(
    const float* __restrict__ emb, const float* __restrict__ sup,
    const unsigned short* __restrict__ w1s, const float* __restrict__ b1,
    const float* __restrict__ W2, const float* __restrict__ b2,
    float* __restrict__ out) {
  __shared__ short8 As16[64 * 64];   // [p 0..63][chunk' 0..63], 65536 B exactly

  const int tid = threadIdx.x;
  const int lane = tid & 63;
  const int wid = tid >> 6;          // 0..7 : 64-h slice (h32 base = wid*2)
  const int l31 = lane & 31;
  const int khalf = lane >> 5;

  const int m0 = blockIdx.x * 16;
  const int n0 = blockIdx.y * 4;

  // ---- staging map: c = 16B k-chunk (0..63), rg = tid>>6 -> 8 rows each ----
  const int c = tid & 63;
  const int rg = tid >> 6;           // == wid (wave-uniform)
  const int nl = rg >> 1;
  const int mq = rg & 1;

  // B prologue for ks=0,1 issued BEFORE staging (overlaps with it)
  const unsigned short* bb = w1s + (wid * 2) * 512 + lane * 8;
  U8 b[3][2];
#pragma unroll
  for (int tj = 0; tj < 2; ++tj) {
    b[0][tj].s = *(const short8*)(bb + (0 * 16 + tj) * 512);
    b[1][tj].s = *(const short8*)(bb + (1 * 16 + tj) * 512);
  }

  // ---- stage 64p x 512k diffs (once) ----
  {
    const float* ep = emb + (n0 + nl) * DD + c * 8;
    const float4 e0 = *(const float4*)ep;
    const float4 e1 = *(const float4*)(ep + 4);
    const float* sbase = sup + (m0 + mq * 8) * DD + c * 8;
#pragma unroll
    for (int j = 0; j < 8; ++j) {
      const float4 s0 = *(const float4*)(sbase + j * DD);
      const float4 s1 = *(const float4*)(sbase + j * DD + 4);
      const int p = rg * 8 + j;                 // p&7 == j
      As16[p * 64 + (c ^ j)] = packdiff(e0, e1, s0, s1);
    }
  }
  __syncthreads();  // barrier 1: tile visible

  // ---- barrier-free K-loop: 32 steps of 16 k ----
  const int ar0 = (0 + l31) * 64;    // A row base, am=0 (short8 units)
  const int ar1 = (32 + l31) * 64;
  const int ax = l31 & 7;            // read-side chunk XOR (p&7 == l31&7)

  f32x16 acc[2][2] = {};
  U8 a[2][2];
  a[0][0].s = As16[ar0 + (khalf ^ ax)];
  a[0][1].s = As16[ar1 + (khalf ^ ax)];

#pragma unroll
  for (int ks = 0; ks < 32; ++ks) {
    const int cur = ks & 1;
    if (ks < 31) {  // A lookahead depth 1 (LDS)
      const int cc = ((ks + 1) * 2 + khalf) ^ ax;
      a[cur ^ 1][0].s = As16[ar0 + cc];
      a[cur ^ 1][1].s = As16[ar1 + cc];
    }
    if (ks + 2 < 32) {  // B lookahead depth 2 (global/L2)
#pragma unroll
      for (int tj = 0; tj < 2; ++tj)
        b[(ks + 2) % 3][tj].s = *(const short8*)(bb + ((ks + 2) * 16 + tj) * 512);
    }
#pragma unroll
    for (int am = 0; am < 2; ++am)
#pragma unroll
      for (int tj = 0; tj < 2; ++tj)
        acc[am][tj] = __builtin_amdgcn_mfma_f32_32x32x16_bf16(
            a[cur][am].b, b[ks % 3][tj].b, acc[am][tj], 0, 0, 0);
  }

  // ---- epilogue: s = sum_{64 h} relu(C+b1)*W2; cross-wave psums reduce ----
  float b1v[2], w2v[2];
#pragma unroll
  for (int tj = 0; tj < 2; ++tj) {
    const int h = (wid * 2 + tj) * 32 + l31;   // C/D: col = lane&31
    b1v[tj] = b1[h];
    w2v[tj] = W2[h];
  }
  __syncthreads();  // barrier 2: all As16 reads done before aliasing
  float* psums = (float*)As16;  // [64 pairs][8 waves]
#pragma unroll
  for (int am = 0; am < 2; ++am) {
#pragma unroll
    for (int r = 0; r < 16; ++r) {
      float s = fmaxf(acc[am][0][r] + b1v[0], 0.f) * w2v[0] +
                fmaxf(acc[am][1][r] + b1v[1], 0.f) * w2v[1];
      s += __shfl_xor(s, 1, 64);
      s += __shfl_xor(s, 2, 64);
      s += __shfl_xor(s, 4, 64);
      s += __shfl_xor(s, 8, 64);
      s += __shfl_xor(s, 16, 64);
      if (l31 == 0) {
        const int row32 = (r & 3) + 8 * (r >> 2) + 4 * khalf;  // C/D row map
        psums[(am * 32 + row32) * 8 + wid] = s;
      }
    }
  }
  __syncthreads();  // barrier 3
  if (tid < 64) {
    float t = b2[0];
#pragma unroll
    for (int w = 0; w < 8; ++w) t += psums[tid * 8 + w];
    out[(n0 + (tid >> 4)) * M_S + m0 + (tid & 15)] = 1.f / (1.f + __expf(-t));
  }
}

extern "C" void kernel_launch(void* const* d_in, const int* in_sizes, int n_in,
                              void* d_out, int out_size, void* d_ws, size_t ws_size,
                              hipStream_t stream) {
  const float* emb = (const float*)d_in[0];
  const float* sup = (const float*)d_in[1];
  const float* W1  = (const float*)d_in[2];
  const float* b1  = (const float*)d_in[3];
  const float* W2  = (const float*)d_in[4];
  const float* b2  = (const float*)d_in[5];
  float* out = (float*)d_out;
  unsigned short* w1s = (unsigned short*)d_ws;  // 512 KB fragment-ordered W1

  prep_w1s<<<32, 512, 0, stream>>>(W1, w1s);
  support_kernel<<<dim3(M_S / 16, N_Q / 4), 512, 0, stream>>>(
      emb, sup, w1s, b1, W2, b2, out);
}

// Round 12
// 234.275 us; speedup vs baseline: 1.0811x; 1.0076x over previous
//
#include <hip/hip_runtime.h>
#include <hip/hip_bf16.h>

#define N_Q 256
#define M_S 1024
#define DD 512
#define HH 512

typedef __attribute__((ext_vector_type(8))) short short8;
typedef __attribute__((ext_vector_type(8))) __bf16 bf16x8;
typedef __attribute__((ext_vector_type(16))) float f32x16;
typedef __attribute__((ext_vector_type(2))) __bf16 bf16x2;

union U8 { short8 s; bf16x8 b; };

__device__ __forceinline__ unsigned short f2bf(float f) {
  unsigned int u = __float_as_uint(f);
  u += 0x7FFFu + ((u >> 16) & 1u);
  return (unsigned short)(u >> 16);
}

__device__ __forceinline__ short8 pack8(const float* d) {
#if defined(__has_builtin) && __has_builtin(__builtin_amdgcn_cvt_pk_bf16_f32)
  short8 r;
#pragma unroll
  for (int i = 0; i < 4; ++i) {
    union { bf16x2 v; short s[2]; } u;
    u.v = __builtin_amdgcn_cvt_pk_bf16_f32(d[2 * i], d[2 * i + 1]);
    r[2 * i] = u.s[0];
    r[2 * i + 1] = u.s[1];
  }
  return r;
#else
  short8 r;
#pragma unroll
  for (int i = 0; i < 8; ++i) r[i] = (short)f2bf(d[i]);
  return r;
#endif
}

__device__ __forceinline__ short8 packdiff(float4 e0, float4 e1, float4 s0, float4 s1) {
  float d[8];
  d[0] = fabsf(e0.x - s0.x); d[1] = fabsf(e0.y - s0.y);
  d[2] = fabsf(e0.z - s0.z); d[3] = fabsf(e0.w - s0.w);
  d[4] = fabsf(e1.x - s1.x); d[5] = fabsf(e1.y - s1.y);
  d[6] = fabsf(e1.z - s1.z); d[7] = fabsf(e1.w - s1.w);
  return pack8(d);
}

// W1 [D][H] fp32 -> w1s in MFMA-B-fragment order (verified R3-R11), LDS-transposed.
__global__ __launch_bounds__(512) void prep_w1s(const float* __restrict__ W1,
                                                unsigned short* __restrict__ w1s) {
  __shared__ float tile[16 * 516];
  const int t = threadIdx.x;
  const int kc = blockIdx.x;         // 0..31
  const float* src = W1 + kc * 16 * HH;
#pragma unroll
  for (int pass = 0; pass < 4; ++pass) {
    const int fi = pass * 2048 + t * 4;
    const float4 v = *(const float4*)(src + fi);
    *(float4*)&tile[(fi >> 9) * 516 + (fi & 511)] = v;
  }
  __syncthreads();
  const int l = t & 63, h32g = t >> 6;
  const int l31 = l & 31, kh = l >> 5;
#pragma unroll
  for (int i = 0; i < 2; ++i) {
    const int h32 = i * 8 + h32g;
    short8 v;
#pragma unroll
    for (int j = 0; j < 8; ++j)
      v[j] = (short)f2bf(tile[(kh * 8 + j) * 516 + h32 * 32 + l31]);
    *(short8*)(w1s + (kc * 16 + h32) * 512 + l * 8) = v;
  }
}

// R12 = R8/R11 structure with B-prefetch depth 4 (5-slot rotation) at
// 3 waves/SIMD. Block: 512 thr = 8 waves, tile 64p x 512h x K=512, A staged
// once in 64 KB LDS [p][c^(p&7)]. Wave 64p x 64h -> acc[2][2] = 64 AGPR.
__global__ __launch_bounds__(512, 3) void support_kernel(
    const float* __restrict__ emb, const float* __restrict__ sup,
    const unsigned short* __restrict__ w1s, const float* __restrict__ b1,
    const float* __restrict__ W2, const float* __restrict__ b2,
    float* __restrict__ out) {
  __shared__ short8 As16[64 * 64];   // 65536 B exactly

  const int tid = threadIdx.x;
  const int lane = tid & 63;
  const int wid = tid >> 6;          // 0..7 : 64-h slice
  const int l31 = lane & 31;
  const int khalf = lane >> 5;

  const int m0 = blockIdx.x * 16;
  const int n0 = blockIdx.y * 4;

  const int c = tid & 63;
  const int rg = tid >> 6;
  const int nl = rg >> 1;
  const int mq = rg & 1;

  // B prologue: 4 steps in flight before/through staging
  const unsigned short* bb = w1s + (wid * 2) * 512 + lane * 8;
  U8 b[5][2];
#pragma unroll
  for (int pk = 0; pk < 4; ++pk)
#pragma unroll
    for (int tj = 0; tj < 2; ++tj)
      b[pk][tj].s = *(const short8*)(bb + (pk * 16 + tj) * 512);

  // ---- stage 64p x 512k diffs (once) ----
  {
    const float* ep = emb + (n0 + nl) * DD + c * 8;
    const float4 e0 = *(const float4*)ep;
    const float4 e1 = *(const float4*)(ep + 4);
    const float* sbase = sup + (m0 + mq * 8) * DD + c * 8;
#pragma unroll
    for (int j = 0; j < 8; ++j) {
      const float4 s0 = *(const float4*)(sbase + j * DD);
      const float4 s1 = *(const float4*)(sbase + j * DD + 4);
      const int p = rg * 8 + j;                 // p&7 == j
      As16[p * 64 + (c ^ j)] = packdiff(e0, e1, s0, s1);
    }
  }
  __syncthreads();  // barrier 1

  const int ar0 = (0 + l31) * 64;
  const int ar1 = (32 + l31) * 64;
  const int ax = l31 & 7;

  f32x16 acc[2][2] = {};
  U8 a[2][2];
  a[0][0].s = As16[ar0 + (khalf ^ ax)];
  a[0][1].s = As16[ar1 + (khalf ^ ax)];

#pragma unroll
  for (int ks = 0; ks < 32; ++ks) {
    const int cur = ks & 1;
    if (ks < 31) {  // A lookahead depth 1 (LDS)
      const int cc = ((ks + 1) * 2 + khalf) ^ ax;
      a[cur ^ 1][0].s = As16[ar0 + cc];
      a[cur ^ 1][1].s = As16[ar1 + cc];
    }
    if (ks + 4 < 32) {  // B lookahead depth 4 (global/L2)
#pragma unroll
      for (int tj = 0; tj < 2; ++tj)
        b[(ks + 4) % 5][tj].s = *(const short8*)(bb + ((ks + 4) * 16 + tj) * 512);
    }
#pragma unroll
    for (int am = 0; am < 2; ++am)
#pragma unroll
      for (int tj = 0; tj < 2; ++tj)
        acc[am][tj] = __builtin_amdgcn_mfma_f32_32x32x16_bf16(
            a[cur][am].b, b[ks % 5][tj].b, acc[am][tj], 0, 0, 0);
  }

  // ---- epilogue ----
  float b1v[2], w2v[2];
#pragma unroll
  for (int tj = 0; tj < 2; ++tj) {
    const int h = (wid * 2 + tj) * 32 + l31;   // C/D: col = lane&31
    b1v[tj] = b1[h];
    w2v[tj] = W2[h];
  }
  __syncthreads();  // barrier 2
  float* psums = (float*)As16;  // [64 pairs][8 waves]
#pragma unroll
  for (int am = 0; am < 2; ++am) {
#pragma unroll
    for (int r = 0; r < 16; ++r) {
      float s = fmaxf(acc[am][0][r] + b1v[0], 0.f) * w2v[0] +
                fmaxf(acc[am][1][r] + b1v[1], 0.f) * w2v[1];
      s += __shfl_xor(s, 1, 64);
      s += __shfl_xor(s, 2, 64);
      s += __shfl_xor(s, 4, 64);
      s += __shfl_xor(s, 8, 64);
      s += __shfl_xor(s, 16, 64);
      if (l31 == 0) {
        const int row32 = (r & 3) + 8 * (r >> 2) + 4 * khalf;  // C/D row map
        psums[(am * 32 + row32) * 8 + wid] = s;
      }
    }
  }
  __syncthreads();  // barrier 3
  if (tid < 64) {
    float t = b2[0];
#pragma unroll
    for (int w = 0; w < 8; ++w) t += psums[tid * 8 + w];
    out[(n0 + (tid >> 4)) * M_S + m0 + (tid & 15)] = 1.f / (1.f + __expf(-t));
  }
}

extern "C" void kernel_launch(void* const* d_in, const int* in_sizes, int n_in,
                              void* d_out, int out_size, void* d_ws, size_t ws_size,
                              hipStream_t stream) {
  const float* emb = (const float*)d_in[0];
  const float* sup = (const float*)d_in[1];
  const float* W1  = (const float*)d_in[2];
  const float* b1  = (const float*)d_in[3];
  const float* W2  = (const float*)d_in[4];
  const float* b2  = (const float*)d_in[5];
  float* out = (float*)d_out;
  unsigned short* w1s = (unsigned short*)d_ws;

  prep_w1s<<<32, 512, 0, stream>>>(W1, w1s);
  support_kernel<<<dim3(M_S / 16, N_Q / 4), 512, 0, stream>>>(
      emb, sup, w1s, b1, W2, b2, out);
}